// Round 5
// baseline (311.448 us; speedup 1.0000x reference)
//
#include <hip/hip_runtime.h>
#include <math.h>

#define BB 64
#define SS 2048
#define FF 1024
#define HH 1024
#define NCHUNK 32

// ---- workspace layout (float offsets) ----
#define WS_PL    0                          // 2048
#define WS_CNT   2048                       // 64 (ints)
#define WS_IDX   (2048+64)                  // B*SS ints = 131072 (+64 pad)
#define WS_XT    (WS_IDX+131072+64)         // 65536 : xT[f][b]
#define WS_HT    (WS_XT+65536)              // 65536 : hT[k][b]
#define WS_X2T   (WS_HT+65536)              // 65536 : x2T[j][b]
#define WS_OUTP  (WS_X2T+65536)             // 65536 : outp[j][b]
#define WS_PACC  (WS_OUTP+65536)            // 2048*1024 = 2097152

__device__ __forceinline__ float sigm(float x){ return 1.f/(1.f + __expf(-x)); }

// ---------- M: mask compaction (per b): idx list of unmasked s, cnt, score pre-fill ----------
__global__ __launch_bounds__(256) void kM(const int* __restrict__ mask,
                                          int* __restrict__ idx,
                                          int* __restrict__ cnt,
                                          float* __restrict__ attw)
{
    int b = blockIdx.x;
    int tid = threadIdx.x, lane = tid & 63, w = tid >> 6;
    const int* mrow = mask + b*SS;
    unsigned long long lmask = (1ull << lane) - 1ull;
    __shared__ int wcnt[4];
    unsigned long long bal[8];
    int pred[8];
    int cw = 0;
    #pragma unroll
    for (int r = 0; r < 8; ++r){
        int s = w*512 + r*64 + lane;
        pred[r] = (mrow[s] != 0);
        attw[b*SS + s] = -1e10f;            // masked rows keep this; kC exp -> 0
        bal[r] = __ballot(pred[r]);
        cw += (int)__popcll(bal[r]);
    }
    if (lane == 0) wcnt[w] = cw;
    __syncthreads();
    int off = 0;
    #pragma unroll
    for (int q = 0; q < 4; ++q) if (q < w) off += wcnt[q];
    int* idxb = idx + b*SS;
    #pragma unroll
    for (int r = 0; r < 8; ++r){
        int s = w*512 + r*64 + lane;
        int pfx = (int)__popcll(bal[r] & lmask);
        if (pred[r]) idxb[off + pfx] = s;
        off += (int)__popcll(bal[r]);
    }
    if (tid == 0) cnt[b] = wcnt[0]+wcnt[1]+wcnt[2]+wcnt[3];
}

// ---------- B: fused scores + softmax accumulation over compacted rows (branch-free loop) ----------
__global__ __launch_bounds__(256) void kB(const float* __restrict__ enc,
                                          const float* __restrict__ attn_W,
                                          const float* __restrict__ input,
                                          const float* __restrict__ hidden,
                                          const float* __restrict__ attn_b,
                                          const int* __restrict__ idx,
                                          const int* __restrict__ cnt,
                                          float* __restrict__ scores_out,
                                          float* __restrict__ pacc,
                                          float* __restrict__ pl)
{
    const int tid  = threadIdx.x;
    const int lane = tid & 63;
    const int w    = tid >> 6;
    const int b    = blockIdx.x >> 5;
    const int c    = blockIdx.x & 31;

    const float4* we4 = (const float4*)attn_W;
    const float4 we0 = we4[lane], we1 = we4[64+lane], we2 = we4[128+lane], we3 = we4[192+lane];

    // per-wave redundant base[b] = h.w_h + input*w_i + attn_b
    const float4* h4  = (const float4*)(hidden + (size_t)b*HH);
    const float4* wh4 = (const float4*)(attn_W + FF);
    float4 hv0 = h4[lane], hv1 = h4[64+lane], hv2 = h4[128+lane], hv3 = h4[192+lane];
    float4 wv0 = wh4[lane], wv1 = wh4[64+lane], wv2 = wh4[128+lane], wv3 = wh4[192+lane];
    float bp = hv0.x*wv0.x + hv0.y*wv0.y + hv0.z*wv0.z + hv0.w*wv0.w
             + hv1.x*wv1.x + hv1.y*wv1.y + hv1.z*wv1.z + hv1.w*wv1.w
             + hv2.x*wv2.x + hv2.y*wv2.y + hv2.z*wv2.z + hv2.w*wv2.w
             + hv3.x*wv3.x + hv3.y*wv3.y + hv3.z*wv3.z + hv3.w*wv3.w;
    #pragma unroll
    for (int off=32; off; off>>=1) bp += __shfl_xor(bp, off);
    const float bb = bp + input[b]*attn_W[FF+HH] + attn_b[0];

    // this block's slice of the compacted list
    int n = cnt[b];
    int per = (n + NCHUNK - 1) >> 5;
    int i0 = c * per; if (i0 > n) i0 = n;
    int i1 = i0 + per; if (i1 > n) i1 = n;
    int len = i1 - i0;
    int perw = (len + 3) >> 2;
    int iw0 = i0 + w * perw;
    int iw1 = iw0 + perw; if (iw1 > i1) iw1 = i1;
    if (iw0 > i1) iw0 = i1;

    const int* idxb = idx + b*SS;
    const float4* encb = (const float4*)(enc + (size_t)b*SS*FF);

    float l = 0.f;
    float4 a0 = make_float4(0,0,0,0), a1 = a0, a2 = a0, a3 = a0;

    int i = iw0;
    for (; i + 2 <= iw1; i += 2){
        int sA = idxb[i], sB = idxb[i+1];
        const float4* rA = encb + (size_t)sA*(FF/4);
        const float4* rB = encb + (size_t)sB*(FF/4);
        float4 e0 = rA[lane], e1 = rA[64+lane], e2 = rA[128+lane], e3 = rA[192+lane];
        float4 f0 = rB[lane], f1 = rB[64+lane], f2 = rB[128+lane], f3 = rB[192+lane];
        float da = (e0.x*we0.x + e0.y*we0.y + e0.z*we0.z + e0.w*we0.w)
                 + (e1.x*we1.x + e1.y*we1.y + e1.z*we1.z + e1.w*we1.w)
                 + (e2.x*we2.x + e2.y*we2.y + e2.z*we2.z + e2.w*we2.w)
                 + (e3.x*we3.x + e3.y*we3.y + e3.z*we3.z + e3.w*we3.w);
        float db = (f0.x*we0.x + f0.y*we0.y + f0.z*we0.z + f0.w*we0.w)
                 + (f1.x*we1.x + f1.y*we1.y + f1.z*we1.z + f1.w*we1.w)
                 + (f2.x*we2.x + f2.y*we2.y + f2.z*we2.z + f2.w*we2.w)
                 + (f3.x*we3.x + f3.y*we3.y + f3.z*we3.z + f3.w*we3.w);
        #pragma unroll
        for (int off=32; off; off>>=1){ da += __shfl_xor(da, off); db += __shfl_xor(db, off); }
        float scA = da + bb, scB = db + bb;
        float pA = __expf(scA), pB = __expf(scB);
        l += pA + pB;
        a0.x += pA*e0.x + pB*f0.x; a0.y += pA*e0.y + pB*f0.y; a0.z += pA*e0.z + pB*f0.z; a0.w += pA*e0.w + pB*f0.w;
        a1.x += pA*e1.x + pB*f1.x; a1.y += pA*e1.y + pB*f1.y; a1.z += pA*e1.z + pB*f1.z; a1.w += pA*e1.w + pB*f1.w;
        a2.x += pA*e2.x + pB*f2.x; a2.y += pA*e2.y + pB*f2.y; a2.z += pA*e2.z + pB*f2.z; a2.w += pA*e2.w + pB*f2.w;
        a3.x += pA*e3.x + pB*f3.x; a3.y += pA*e3.y + pB*f3.y; a3.z += pA*e3.z + pB*f3.z; a3.w += pA*e3.w + pB*f3.w;
        if (lane == 0){ scores_out[b*SS + sA] = scA; scores_out[b*SS + sB] = scB; }
    }
    if (i < iw1){
        int sA = idxb[i];
        const float4* rA = encb + (size_t)sA*(FF/4);
        float4 e0 = rA[lane], e1 = rA[64+lane], e2 = rA[128+lane], e3 = rA[192+lane];
        float da = (e0.x*we0.x + e0.y*we0.y + e0.z*we0.z + e0.w*we0.w)
                 + (e1.x*we1.x + e1.y*we1.y + e1.z*we1.z + e1.w*we1.w)
                 + (e2.x*we2.x + e2.y*we2.y + e2.z*we2.z + e2.w*we2.w)
                 + (e3.x*we3.x + e3.y*we3.y + e3.z*we3.z + e3.w*we3.w);
        #pragma unroll
        for (int off=32; off; off>>=1) da += __shfl_xor(da, off);
        float scA = da + bb;
        float pA = __expf(scA);
        l += pA;
        a0.x += pA*e0.x; a0.y += pA*e0.y; a0.z += pA*e0.z; a0.w += pA*e0.w;
        a1.x += pA*e1.x; a1.y += pA*e1.y; a1.z += pA*e1.z; a1.w += pA*e1.w;
        a2.x += pA*e2.x; a2.y += pA*e2.y; a2.z += pA*e2.z; a2.w += pA*e2.w;
        a3.x += pA*e3.x; a3.y += pA*e3.y; a3.z += pA*e3.z; a3.w += pA*e3.w;
        if (lane == 0) scores_out[b*SS + sA] = scA;
    }

    __shared__ float4 sacc[4][256];
    __shared__ float sl[4];
    if (lane==0) sl[w] = l;
    sacc[w][lane]     = a0;
    sacc[w][64+lane]  = a1;
    sacc[w][128+lane] = a2;
    sacc[w][192+lane] = a3;
    __syncthreads();
    float4 tot = sacc[0][tid];
    #pragma unroll
    for (int q=1;q<4;q++){ float4 u = sacc[q][tid]; tot.x+=u.x; tot.y+=u.y; tot.z+=u.z; tot.w+=u.w; }
    ((float4*)(pacc + (size_t)blockIdx.x*FF))[tid] = tot;
    if (tid==0) pl[blockIdx.x] = sl[0]+sl[1]+sl[2]+sl[3];
}

// ---------- C: merge partials -> xT[f][b]; q==0: scores->weights; q==1: hT transpose ----------
__global__ __launch_bounds__(256) void kC(const float* __restrict__ pacc,
                                          const float* __restrict__ pl,
                                          const float* __restrict__ hidden,
                                          float* __restrict__ xT,
                                          float* __restrict__ wout,
                                          float* __restrict__ hT)
{
    int b = blockIdx.x >> 2, q = blockIdx.x & 3, tid = threadIdx.x;
    float L = 0.f;
    #pragma unroll
    for (int c=0;c<NCHUNK;c++) L += pl[b*NCHUNK+c];
    float invL = 1.f/L;

    int f = q*256 + tid;
    float a = 0.f;
    #pragma unroll
    for (int c=0;c<NCHUNK;c++) a += pacc[((size_t)(b*NCHUNK+c))*FF + f];
    xT[(size_t)f*BB + b] = a*invL;

    if (q == 0){
        for (int t = tid; t < SS; t += 256){
            int idx2 = b*SS + t;
            wout[idx2] = __expf(wout[idx2]) * invL;
        }
    } else if (q == 1){
        for (int k = tid; k < HH; k += 256) hT[(size_t)k*BB + b] = hidden[(size_t)b*HH + k];
    }
}

// ---------- E: x2T[j][b] = relu(x·cW[j] + input*cW[j][0] + cb[j]); 4-way k-split ----------
__global__ __launch_bounds__(256) void kE(const float* __restrict__ xT,
                                          const float* __restrict__ input,
                                          const float* __restrict__ cW,
                                          const float* __restrict__ cb,
                                          float* __restrict__ x2T)
{
    int lane = threadIdx.x & 63;
    int wu = __builtin_amdgcn_readfirstlane(threadIdx.x >> 6);
    int j = blockIdx.x;
    const float* wrow = cW + (size_t)j*(FF+1);
    int kb = wu*256;
    float accA = 0.f, accB = 0.f;
    #pragma unroll 8
    for (int t=0; t<256; t+=2){
        accA += xT[(size_t)(kb+t)*BB   + lane] * wrow[1+kb+t];
        accB += xT[(size_t)(kb+t+1)*BB + lane] * wrow[2+kb+t];
    }
    __shared__ float sred[4][64];
    sred[wu][lane] = accA + accB;
    __syncthreads();
    if (wu == 0){
        float s = sred[0][lane]+sred[1][lane]+sred[2][lane]+sred[3][lane]
                + input[lane]*wrow[0] + cb[j];
        x2T[(size_t)j*BB + lane] = fmaxf(s, 0.f);
    }
}

// ---------- F: fused GRU column j — 6 dot products (4-way k-split), gates, h_new, out partial ----------
__global__ __launch_bounds__(256) void kF(const float* __restrict__ x2T,
                                          const float* __restrict__ hT,
                                          const float* __restrict__ W_ih,
                                          const float* __restrict__ W_hh,
                                          const float* __restrict__ b_ih,
                                          const float* __restrict__ b_hh,
                                          const float* __restrict__ out_W,
                                          float* __restrict__ hnew,
                                          float* __restrict__ outp)
{
    int lane = threadIdx.x & 63;
    int wu = __builtin_amdgcn_readfirstlane(threadIdx.x >> 6);
    int j = blockIdx.x;

    const float* wi0 = W_ih + (size_t)j*HH;
    const float* wi1 = W_ih + (size_t)(HH+j)*HH;
    const float* wi2 = W_ih + (size_t)(2*HH+j)*HH;
    const float* wh0 = W_hh + (size_t)j*HH;
    const float* wh1 = W_hh + (size_t)(HH+j)*HH;
    const float* wh2 = W_hh + (size_t)(2*HH+j)*HH;

    int kb = wu*256;
    float ai0=0.f, ai1=0.f, ai2=0.f, ah0=0.f, ah1=0.f, ah2=0.f;
    #pragma unroll 4
    for (int t=0; t<256; ++t){
        int k = kb + t;
        float xv = x2T[(size_t)k*BB + lane];
        float hv = hT [(size_t)k*BB + lane];
        ai0 += xv*wi0[k]; ai1 += xv*wi1[k]; ai2 += xv*wi2[k];
        ah0 += hv*wh0[k]; ah1 += hv*wh1[k]; ah2 += hv*wh2[k];
    }

    __shared__ float sred[4][6][64];
    sred[wu][0][lane]=ai0; sred[wu][1][lane]=ai1; sred[wu][2][lane]=ai2;
    sred[wu][3][lane]=ah0; sred[wu][4][lane]=ah1; sred[wu][5][lane]=ah2;
    __syncthreads();
    if (wu == 0){
        float g0 = sred[0][0][lane]+sred[1][0][lane]+sred[2][0][lane]+sred[3][0][lane];
        float g1 = sred[0][1][lane]+sred[1][1][lane]+sred[2][1][lane]+sred[3][1][lane];
        float g2 = sred[0][2][lane]+sred[1][2][lane]+sred[2][2][lane]+sred[3][2][lane];
        float g3 = sred[0][3][lane]+sred[1][3][lane]+sred[2][3][lane]+sred[3][3][lane];
        float g4 = sred[0][4][lane]+sred[1][4][lane]+sred[2][4][lane]+sred[3][4][lane];
        float g5 = sred[0][5][lane]+sred[1][5][lane]+sred[2][5][lane]+sred[3][5][lane];
        float r = sigm(g0+b_ih[j]       + g3+b_hh[j]);
        float z = sigm(g1+b_ih[HH+j]    + g4+b_hh[HH+j]);
        float n = tanhf(g2+b_ih[2*HH+j] + r*(g5+b_hh[2*HH+j]));
        float hold = hT[(size_t)j*BB + lane];
        float hn = (1.f - z)*n + z*hold;
        hnew[(size_t)lane*HH + j] = hn;
        outp[(size_t)j*BB + lane] = fmaxf(hn, 0.f) * out_W[j];
    }
}

// ---------- G: out[b] = sum_j outp[j][b] + out_b ----------
__global__ __launch_bounds__(256) void kG(const float* __restrict__ outp,
                                          const float* __restrict__ out_b,
                                          float* __restrict__ out)
{
    int tid = threadIdx.x, bl = tid & 63, q = tid >> 6;
    float s = 0.f;
    for (int j = q*256; j < q*256+256; ++j) s += outp[(size_t)j*BB + bl];
    __shared__ float red[4][64];
    red[q][bl] = s;
    __syncthreads();
    if (q == 0) out[bl] = red[0][bl]+red[1][bl]+red[2][bl]+red[3][bl] + out_b[0];
}

extern "C" void kernel_launch(void* const* d_in, const int* in_sizes, int n_in,
                              void* d_out, int out_size, void* d_ws, size_t ws_size,
                              hipStream_t stream) {
    const float* input     = (const float*)d_in[0];
    const float* hidden    = (const float*)d_in[1];
    const float* enc       = (const float*)d_in[2];
    const int*   mask      = (const int*)  d_in[3];
    const float* attn_W    = (const float*)d_in[4];
    const float* attn_b    = (const float*)d_in[5];
    const float* combine_W = (const float*)d_in[6];
    const float* combine_b = (const float*)d_in[7];
    const float* W_ih      = (const float*)d_in[8];
    const float* W_hh      = (const float*)d_in[9];
    const float* b_ih      = (const float*)d_in[10];
    const float* b_hh      = (const float*)d_in[11];
    const float* out_W     = (const float*)d_in[12];
    const float* out_b     = (const float*)d_in[13];

    float* out  = (float*)d_out;
    float* hnew = out + 64;            // (1,B,H)
    float* attw = out + 64 + BB*HH;    // (B,S,1) — raw scores between kM/kB and kC
    float* ws   = (float*)d_ws;
    int*   wsi  = (int*)d_ws;

    kM<<<64,   256, 0, stream>>>(mask, wsi+WS_IDX, wsi+WS_CNT, attw);
    kB<<<BB*NCHUNK, 256, 0, stream>>>(enc, attn_W, input, hidden, attn_b,
                                      wsi+WS_IDX, wsi+WS_CNT, attw, ws+WS_PACC, ws+WS_PL);
    kC<<<256,  256, 0, stream>>>(ws+WS_PACC, ws+WS_PL, hidden, ws+WS_XT, attw, ws+WS_HT);
    kE<<<1024, 256, 0, stream>>>(ws+WS_XT, input, combine_W, combine_b, ws+WS_X2T);
    kF<<<1024, 256, 0, stream>>>(ws+WS_X2T, ws+WS_HT, W_ih, W_hh, b_ih, b_hh, out_W,
                                 hnew, ws+WS_OUTP);
    kG<<<1,    256, 0, stream>>>(ws+WS_OUTP, out_b, out);
}

// Round 6
// 300.213 us; speedup vs baseline: 1.0374x; 1.0374x over previous
//
#include <hip/hip_runtime.h>
#include <math.h>

#define BB 64
#define SS 2048
#define FF 1024
#define HH 1024
#define NCHUNK 32
#define CHUNK_S 64    // SS/NCHUNK
#define RPW 16        // rows per wave (CHUNK_S/4)

// ---- workspace layout (float offsets) ----
#define WS_PL    0                        // 2048
#define WS_XT    2048                     // 65536 : xT[f][b]
#define WS_HT    (WS_XT+65536)            // 65536 : hT[k][b]
#define WS_X2T   (WS_HT+65536)            // 65536 : x2T[j][b]
#define WS_OUTP  (WS_X2T+65536)           // 65536 : outp[j][b]
#define WS_HNT   (WS_OUTP+65536)          // 65536 : hnT[j][b]
#define WS_PACC  (WS_HNT+65536)           // 2048*1024 = 2097152

__device__ __forceinline__ float sigm(float x){ return 1.f/(1.f + __expf(-x)); }

// unaligned-safe float4 load (cW rows have stride 1025 -> only 4B-aligned)
__device__ __forceinline__ float4 ld4u(const float* p){
    float4 v; __builtin_memcpy(&v, p, 16); return v;
}

// ---------- B: fused scores + softmax accumulation (R3-exact: branch-free full stream) ----------
__global__ __launch_bounds__(256) void kB(const float* __restrict__ enc,
                                          const int*   __restrict__ mask,
                                          const float* __restrict__ attn_W,
                                          const float* __restrict__ input,
                                          const float* __restrict__ hidden,
                                          const float* __restrict__ attn_b,
                                          float* __restrict__ scores_out,
                                          float* __restrict__ pacc,
                                          float* __restrict__ pl)
{
    const int tid  = threadIdx.x;
    const int lane = tid & 63;
    const int w    = tid >> 6;
    const int b    = blockIdx.x >> 5;
    const int c    = blockIdx.x & 31;
    const int s0   = c*CHUNK_S + w*RPW;

    const float4* we4 = (const float4*)attn_W;
    const float4 we0 = we4[lane], we1 = we4[64+lane], we2 = we4[128+lane], we3 = we4[192+lane];

    const float4* h4  = (const float4*)(hidden + (size_t)b*HH);
    const float4* wh4 = (const float4*)(attn_W + FF);
    float4 hv0 = h4[lane], hv1 = h4[64+lane], hv2 = h4[128+lane], hv3 = h4[192+lane];
    float4 wv0 = wh4[lane], wv1 = wh4[64+lane], wv2 = wh4[128+lane], wv3 = wh4[192+lane];
    float bp = hv0.x*wv0.x + hv0.y*wv0.y + hv0.z*wv0.z + hv0.w*wv0.w
             + hv1.x*wv1.x + hv1.y*wv1.y + hv1.z*wv1.z + hv1.w*wv1.w
             + hv2.x*wv2.x + hv2.y*wv2.y + hv2.z*wv2.z + hv2.w*wv2.w
             + hv3.x*wv3.x + hv3.y*wv3.y + hv3.z*wv3.z + hv3.w*wv3.w;
    #pragma unroll
    for (int off=32; off; off>>=1) bp += __shfl_xor(bp, off);
    const float bb = bp + input[b]*attn_W[FF+HH] + attn_b[0];

    float l = 0.f;
    float4 a0 = make_float4(0,0,0,0), a1 = a0, a2 = a0, a3 = a0;
    float sc_keep = 0.f;

    const float4* rowbase = (const float4*)(enc + (size_t)(b*SS + s0)*FF);
    const int* mrow = mask + b*SS + s0;

    for (int i=0;i<RPW;i+=2){
        const float4* rowA = rowbase + (size_t)i*(FF/4);
        const float4* rowB = rowA + (FF/4);
        float4 e0 = rowA[lane], e1 = rowA[64+lane], e2 = rowA[128+lane], e3 = rowA[192+lane];
        float4 f0 = rowB[lane], f1 = rowB[64+lane], f2 = rowB[128+lane], f3 = rowB[192+lane];
        int2 mk = *(const int2*)(mrow + i);

        float da = (e0.x*we0.x + e0.y*we0.y + e0.z*we0.z + e0.w*we0.w)
                 + (e1.x*we1.x + e1.y*we1.y + e1.z*we1.z + e1.w*we1.w)
                 + (e2.x*we2.x + e2.y*we2.y + e2.z*we2.z + e2.w*we2.w)
                 + (e3.x*we3.x + e3.y*we3.y + e3.z*we3.z + e3.w*we3.w);
        float db = (f0.x*we0.x + f0.y*we0.y + f0.z*we0.z + f0.w*we0.w)
                 + (f1.x*we1.x + f1.y*we1.y + f1.z*we1.z + f1.w*we1.w)
                 + (f2.x*we2.x + f2.y*we2.y + f2.z*we2.z + f2.w*we2.w)
                 + (f3.x*we3.x + f3.y*we3.y + f3.z*we3.z + f3.w*we3.w);
        #pragma unroll
        for (int off=32; off; off>>=1){ da += __shfl_xor(da, off); db += __shfl_xor(db, off); }
        float sA = da + bb, sB = db + bb;
        if (mk.x == 0) sA = -1e10f;
        if (mk.y == 0) sB = -1e10f;
        sc_keep = (lane == i)   ? sA : sc_keep;
        sc_keep = (lane == i+1) ? sB : sc_keep;
        float pA = __expf(sA), pB = __expf(sB);
        l += pA + pB;
        a0.x += pA*e0.x + pB*f0.x; a0.y += pA*e0.y + pB*f0.y; a0.z += pA*e0.z + pB*f0.z; a0.w += pA*e0.w + pB*f0.w;
        a1.x += pA*e1.x + pB*f1.x; a1.y += pA*e1.y + pB*f1.y; a1.z += pA*e1.z + pB*f1.z; a1.w += pA*e1.w + pB*f1.w;
        a2.x += pA*e2.x + pB*f2.x; a2.y += pA*e2.y + pB*f2.y; a2.z += pA*e2.z + pB*f2.z; a2.w += pA*e2.w + pB*f2.w;
        a3.x += pA*e3.x + pB*f3.x; a3.y += pA*e3.y + pB*f3.y; a3.z += pA*e3.z + pB*f3.z; a3.w += pA*e3.w + pB*f3.w;
    }
    if (lane < RPW) scores_out[b*SS + s0 + lane] = sc_keep;

    __shared__ float4 sacc[4][256];
    __shared__ float sl[4];
    if (lane==0) sl[w] = l;
    sacc[w][lane]     = a0;
    sacc[w][64+lane]  = a1;
    sacc[w][128+lane] = a2;
    sacc[w][192+lane] = a3;
    __syncthreads();
    float4 tot = sacc[0][tid];
    #pragma unroll
    for (int q=1;q<4;q++){ float4 u = sacc[q][tid]; tot.x+=u.x; tot.y+=u.y; tot.z+=u.z; tot.w+=u.w; }
    ((float4*)(pacc + (size_t)blockIdx.x*FF))[tid] = tot;
    if (tid==0) pl[blockIdx.x] = sl[0]+sl[1]+sl[2]+sl[3];
}

// ---------- C: merge partials -> xT[f][b]; q==0: scores->weights; q==1: hT transpose ----------
__global__ __launch_bounds__(256) void kC(const float* __restrict__ pacc,
                                          const float* __restrict__ pl,
                                          const float* __restrict__ hidden,
                                          float* __restrict__ xT,
                                          float* __restrict__ wout,
                                          float* __restrict__ hT)
{
    int b = blockIdx.x >> 2, q = blockIdx.x & 3, tid = threadIdx.x;
    float L = 0.f;
    #pragma unroll
    for (int c=0;c<NCHUNK;c++) L += pl[b*NCHUNK+c];
    float invL = 1.f/L;

    int f = q*256 + tid;
    float a = 0.f;
    #pragma unroll
    for (int c=0;c<NCHUNK;c++) a += pacc[((size_t)(b*NCHUNK+c))*FF + f];
    xT[(size_t)f*BB + b] = a*invL;

    if (q == 0){
        for (int t = tid; t < SS; t += 256){
            int idx2 = b*SS + t;
            wout[idx2] = __expf(wout[idx2]) * invL;
        }
    } else if (q == 1){
        for (int k = tid; k < HH; k += 256) hT[(size_t)k*BB + b] = hidden[(size_t)b*HH + k];
    }
}

// ---------- E: x2T[j][b] = relu(x·cW[j] + input[b]*cW[j][0] + cb[j]) ----------
// 1 column per wave; weights as wave-uniform float4 streams; acts coalesced in VGPRs.
__global__ __launch_bounds__(256) void kE(const float* __restrict__ xT,
                                          const float* __restrict__ input,
                                          const float* __restrict__ cW,
                                          const float* __restrict__ cb,
                                          float* __restrict__ x2T)
{
    int lane = threadIdx.x & 63;
    int w = __builtin_amdgcn_readfirstlane(threadIdx.x >> 6);
    int j = blockIdx.x*4 + w;
    const float* wrow = cW + (size_t)j*(FF+1) + 1;
    float acc = 0.f;
    for (int k0=0; k0<FF; k0+=32){
        float av[32];
        #pragma unroll
        for (int i=0;i<32;++i) av[i] = xT[(size_t)(k0+i)*BB + lane];
        #pragma unroll
        for (int q=0;q<8;++q){
            float4 wv = ld4u(wrow + k0 + q*4);
            acc += av[q*4+0]*wv.x + av[q*4+1]*wv.y + av[q*4+2]*wv.z + av[q*4+3]*wv.w;
        }
    }
    acc += input[lane]*cW[(size_t)j*(FF+1)] + cb[j];
    x2T[(size_t)j*BB + lane] = fmaxf(acc, 0.f);
}

// ---------- F: fused GRU column j — 6 uniform s_load_dwordx4 weight streams, gates, h_new ----------
__global__ __launch_bounds__(256) void kF(const float* __restrict__ x2T,
                                          const float* __restrict__ hT,
                                          const float* __restrict__ W_ih,
                                          const float* __restrict__ W_hh,
                                          const float* __restrict__ b_ih,
                                          const float* __restrict__ b_hh,
                                          const float* __restrict__ out_W,
                                          float* __restrict__ hnT,
                                          float* __restrict__ outp)
{
    int lane = threadIdx.x & 63;
    int w = __builtin_amdgcn_readfirstlane(threadIdx.x >> 6);
    int j = blockIdx.x*4 + w;

    const float* wi0 = W_ih + (size_t)j*HH;
    const float* wi1 = W_ih + (size_t)(HH+j)*HH;
    const float* wi2 = W_ih + (size_t)(2*HH+j)*HH;
    const float* wh0 = W_hh + (size_t)j*HH;
    const float* wh1 = W_hh + (size_t)(HH+j)*HH;
    const float* wh2 = W_hh + (size_t)(2*HH+j)*HH;

    float ai0=0.f, ai1=0.f, ai2=0.f, ah0=0.f, ah1=0.f, ah2=0.f;
    for (int k0=0; k0<HH; k0+=32){
        float xv[32], hv[32];
        #pragma unroll
        for (int i=0;i<32;++i){
            xv[i] = x2T[(size_t)(k0+i)*BB + lane];
            hv[i] = hT [(size_t)(k0+i)*BB + lane];
        }
        #pragma unroll
        for (int q=0;q<8;++q){
            int k = k0 + q*4;
            float4 a0 = *(const float4*)(wi0 + k);
            float4 a1 = *(const float4*)(wi1 + k);
            float4 a2 = *(const float4*)(wi2 + k);
            float4 b0 = *(const float4*)(wh0 + k);
            float4 b1 = *(const float4*)(wh1 + k);
            float4 b2 = *(const float4*)(wh2 + k);
            float x0 = xv[q*4+0], x1 = xv[q*4+1], x2 = xv[q*4+2], x3 = xv[q*4+3];
            float h0 = hv[q*4+0], h1 = hv[q*4+1], h2 = hv[q*4+2], h3 = hv[q*4+3];
            ai0 += x0*a0.x + x1*a0.y + x2*a0.z + x3*a0.w;
            ai1 += x0*a1.x + x1*a1.y + x2*a1.z + x3*a1.w;
            ai2 += x0*a2.x + x1*a2.y + x2*a2.z + x3*a2.w;
            ah0 += h0*b0.x + h1*b0.y + h2*b0.z + h3*b0.w;
            ah1 += h0*b1.x + h1*b1.y + h2*b1.z + h3*b1.w;
            ah2 += h0*b2.x + h1*b2.y + h2*b2.z + h3*b2.w;
        }
    }
    float r = sigm(ai0 + b_ih[j]      + ah0 + b_hh[j]);
    float z = sigm(ai1 + b_ih[HH+j]   + ah1 + b_hh[HH+j]);
    float n = tanhf(ai2 + b_ih[2*HH+j] + r*(ah2 + b_hh[2*HH+j]));
    float hold = hT[(size_t)j*BB + lane];
    float hn = (1.f - z)*n + z*hold;
    hnT[(size_t)j*BB + lane]  = hn;
    outp[(size_t)j*BB + lane] = fmaxf(hn, 0.f) * out_W[j];
}

// ---------- G2: per-b — transpose hnT -> hnew and reduce outp -> out (atomic-free) ----------
__global__ __launch_bounds__(256) void kG2(const float* __restrict__ hnT,
                                           const float* __restrict__ outp,
                                           const float* __restrict__ out_b,
                                           float* __restrict__ hnew,
                                           float* __restrict__ out)
{
    int b = blockIdx.x, tid = threadIdx.x;
    float s = 0.f;
    float4 hvec;
    int j0 = tid*4;
    hvec.x = hnT[(size_t)(j0+0)*BB + b];
    hvec.y = hnT[(size_t)(j0+1)*BB + b];
    hvec.z = hnT[(size_t)(j0+2)*BB + b];
    hvec.w = hnT[(size_t)(j0+3)*BB + b];
    *(float4*)&hnew[(size_t)b*HH + j0] = hvec;
    s += outp[(size_t)(j0+0)*BB + b] + outp[(size_t)(j0+1)*BB + b]
       + outp[(size_t)(j0+2)*BB + b] + outp[(size_t)(j0+3)*BB + b];

    __shared__ float red[256];
    red[tid] = s;
    __syncthreads();
    #pragma unroll
    for (int off=128; off>=1; off>>=1){
        if (tid < off) red[tid] += red[tid+off];
        __syncthreads();
    }
    if (tid == 0) out[b] = red[0] + out_b[0];
}

extern "C" void kernel_launch(void* const* d_in, const int* in_sizes, int n_in,
                              void* d_out, int out_size, void* d_ws, size_t ws_size,
                              hipStream_t stream) {
    const float* input     = (const float*)d_in[0];
    const float* hidden    = (const float*)d_in[1];
    const float* enc       = (const float*)d_in[2];
    const int*   mask      = (const int*)  d_in[3];
    const float* attn_W    = (const float*)d_in[4];
    const float* attn_b    = (const float*)d_in[5];
    const float* combine_W = (const float*)d_in[6];
    const float* combine_b = (const float*)d_in[7];
    const float* W_ih      = (const float*)d_in[8];
    const float* W_hh      = (const float*)d_in[9];
    const float* b_ih      = (const float*)d_in[10];
    const float* b_hh      = (const float*)d_in[11];
    const float* out_W     = (const float*)d_in[12];
    const float* out_b     = (const float*)d_in[13];

    float* out  = (float*)d_out;
    float* hnew = out + 64;            // (1,B,H)
    float* attw = out + 64 + BB*HH;    // (B,S,1) — raw scores between kB and kC
    float* ws   = (float*)d_ws;

    kB <<<BB*NCHUNK, 256, 0, stream>>>(enc, mask, attn_W, input, hidden, attn_b,
                                       attw, ws+WS_PACC, ws+WS_PL);
    kC <<<256, 256, 0, stream>>>(ws+WS_PACC, ws+WS_PL, hidden, ws+WS_XT, attw, ws+WS_HT);
    kE <<<256, 256, 0, stream>>>(ws+WS_XT, input, combine_W, combine_b, ws+WS_X2T);
    kF <<<256, 256, 0, stream>>>(ws+WS_X2T, ws+WS_HT, W_ih, W_hh, b_ih, b_hh, out_W,
                                 ws+WS_HNT, ws+WS_OUTP);
    kG2<<<64,  256, 0, stream>>>(ws+WS_HNT, ws+WS_OUTP, out_b, hnew, out);
}

// Round 7
// 107.813 us; speedup vs baseline: 2.8888x; 2.7846x over previous
//
#include <hip/hip_runtime.h>
#include <math.h>

#define BB 64
#define SS 2048
#define FF 1024
#define HH 1024
#define NCHUNK 32
#define KSPLIT 8
#define KCH 128       // HH/KSPLIT

// ---- workspace layout (float offsets) ----
#define WS_PL    0                        // 2048
#define WS_XT    2048                     // 65536
#define WS_HT    (WS_XT+65536)            // 65536
#define WS_X2T   (WS_HT+65536)            // 65536
#define WS_EPART (WS_X2T+65536)           // 8*1024*64   = 524288
#define WS_GPART (WS_EPART+524288)        // 8*6144*64   = 3145728
#define WS_PACC  (WS_GPART+3145728)       // 2048*1024   = 2097152
#define WS_CNT   (WS_PACC+2097152)        // 64 ints
#define WS_IDX   (WS_CNT+64)              // B*SS ints

__device__ __forceinline__ float sigm(float x){ return 1.f/(1.f + __expf(-x)); }

// ---------- M: mask compaction (per b): idx list of unmasked s, cnt, score pre-fill ----------
__global__ __launch_bounds__(256) void kM(const int* __restrict__ mask,
                                          int* __restrict__ idx,
                                          int* __restrict__ cnt,
                                          float* __restrict__ attw)
{
    int b = blockIdx.x;
    int tid = threadIdx.x, lane = tid & 63, w = tid >> 6;
    const int* mrow = mask + b*SS;
    unsigned long long lmask = (1ull << lane) - 1ull;
    __shared__ int wcnt[4];
    unsigned long long bal[8];
    int pred[8];
    int cw = 0;
    #pragma unroll
    for (int r = 0; r < 8; ++r){
        int s = w*512 + r*64 + lane;
        pred[r] = (mrow[s] != 0);
        attw[b*SS + s] = -1e10f;            // masked rows keep this; kC exp -> 0
        bal[r] = __ballot(pred[r]);
        cw += (int)__popcll(bal[r]);
    }
    if (lane == 0) wcnt[w] = cw;
    __syncthreads();
    int off = 0;
    #pragma unroll
    for (int q = 0; q < 4; ++q) if (q < w) off += wcnt[q];
    int* idxb = idx + b*SS;
    #pragma unroll
    for (int r = 0; r < 8; ++r){
        int s = w*512 + r*64 + lane;
        int pfx = (int)__popcll(bal[r] & lmask);
        if (pred[r]) idxb[off + pfx] = s;
        off += (int)__popcll(bal[r]);
    }
    if (tid == 0) cnt[b] = wcnt[0]+wcnt[1]+wcnt[2]+wcnt[3];
}

// ---------- B: fused scores + softmax accum over compacted rows; indices held in registers ----------
__global__ __launch_bounds__(256) void kB(const float* __restrict__ enc,
                                          const float* __restrict__ attn_W,
                                          const float* __restrict__ input,
                                          const float* __restrict__ hidden,
                                          const float* __restrict__ attn_b,
                                          const int* __restrict__ idx,
                                          const int* __restrict__ cnt,
                                          float* __restrict__ scores_out,
                                          float* __restrict__ pacc,
                                          float* __restrict__ pl)
{
    const int tid  = threadIdx.x;
    const int lane = tid & 63;
    const int w    = tid >> 6;
    const int b    = blockIdx.x >> 5;
    const int c    = blockIdx.x & 31;

    const float4* we4 = (const float4*)attn_W;
    const float4 we0 = we4[lane], we1 = we4[64+lane], we2 = we4[128+lane], we3 = we4[192+lane];

    // per-wave redundant base[b] = h.w_h + input*w_i + attn_b
    const float4* h4  = (const float4*)(hidden + (size_t)b*HH);
    const float4* wh4 = (const float4*)(attn_W + FF);
    float4 hv0 = h4[lane], hv1 = h4[64+lane], hv2 = h4[128+lane], hv3 = h4[192+lane];
    float4 wv0 = wh4[lane], wv1 = wh4[64+lane], wv2 = wh4[128+lane], wv3 = wh4[192+lane];
    float bp = hv0.x*wv0.x + hv0.y*wv0.y + hv0.z*wv0.z + hv0.w*wv0.w
             + hv1.x*wv1.x + hv1.y*wv1.y + hv1.z*wv1.z + hv1.w*wv1.w
             + hv2.x*wv2.x + hv2.y*wv2.y + hv2.z*wv2.z + hv2.w*wv2.w
             + hv3.x*wv3.x + hv3.y*wv3.y + hv3.z*wv3.z + hv3.w*wv3.w;
    #pragma unroll
    for (int off=32; off; off>>=1) bp += __shfl_xor(bp, off);
    const float bb = bp + input[b]*attn_W[FF+HH] + attn_b[0];

    // this block's slice of the compacted list; wave's sub-slice indices -> one register
    int n = cnt[b];
    int per = (n + NCHUNK - 1) >> 5;
    int i0 = c * per; if (i0 > n) i0 = n;
    int i1 = i0 + per; if (i1 > n) i1 = n;
    int len = i1 - i0;
    int perw = (len + 3) >> 2;
    int iw0 = i0 + w * perw;
    int cw = perw;
    if (iw0 > i1) { iw0 = i1; }
    if (iw0 + cw > i1) cw = i1 - iw0;
    if (cw < 0) cw = 0;

    int myidx = 0;
    if (lane < cw) myidx = idx[b*SS + iw0 + lane];   // <=16 rows per wave, one coalesced load

    const float4* encb = (const float4*)(enc + (size_t)b*SS*FF);

    float l = 0.f;
    float4 a0 = make_float4(0,0,0,0), a1 = a0, a2 = a0, a3 = a0;

    int i = 0;
    for (; i + 2 <= cw; i += 2){
        int sA = __builtin_amdgcn_readlane(myidx, i);
        int sB = __builtin_amdgcn_readlane(myidx, i+1);
        const float4* rA = encb + (size_t)sA*(FF/4);
        const float4* rB = encb + (size_t)sB*(FF/4);
        float4 e0 = rA[lane], e1 = rA[64+lane], e2 = rA[128+lane], e3 = rA[192+lane];
        float4 f0 = rB[lane], f1 = rB[64+lane], f2 = rB[128+lane], f3 = rB[192+lane];
        float da = (e0.x*we0.x + e0.y*we0.y + e0.z*we0.z + e0.w*we0.w)
                 + (e1.x*we1.x + e1.y*we1.y + e1.z*we1.z + e1.w*we1.w)
                 + (e2.x*we2.x + e2.y*we2.y + e2.z*we2.z + e2.w*we2.w)
                 + (e3.x*we3.x + e3.y*we3.y + e3.z*we3.z + e3.w*we3.w);
        float db = (f0.x*we0.x + f0.y*we0.y + f0.z*we0.z + f0.w*we0.w)
                 + (f1.x*we1.x + f1.y*we1.y + f1.z*we1.z + f1.w*we1.w)
                 + (f2.x*we2.x + f2.y*we2.y + f2.z*we2.z + f2.w*we2.w)
                 + (f3.x*we3.x + f3.y*we3.y + f3.z*we3.z + f3.w*we3.w);
        #pragma unroll
        for (int off=32; off; off>>=1){ da += __shfl_xor(da, off); db += __shfl_xor(db, off); }
        float scA = da + bb, scB = db + bb;
        float pA = __expf(scA), pB = __expf(scB);
        l += pA + pB;
        a0.x += pA*e0.x + pB*f0.x; a0.y += pA*e0.y + pB*f0.y; a0.z += pA*e0.z + pB*f0.z; a0.w += pA*e0.w + pB*f0.w;
        a1.x += pA*e1.x + pB*f1.x; a1.y += pA*e1.y + pB*f1.y; a1.z += pA*e1.z + pB*f1.z; a1.w += pA*e1.w + pB*f1.w;
        a2.x += pA*e2.x + pB*f2.x; a2.y += pA*e2.y + pB*f2.y; a2.z += pA*e2.z + pB*f2.z; a2.w += pA*e2.w + pB*f2.w;
        a3.x += pA*e3.x + pB*f3.x; a3.y += pA*e3.y + pB*f3.y; a3.z += pA*e3.z + pB*f3.z; a3.w += pA*e3.w + pB*f3.w;
        if (lane == 0){ scores_out[b*SS + sA] = scA; scores_out[b*SS + sB] = scB; }
    }
    if (i < cw){
        int sA = __builtin_amdgcn_readlane(myidx, i);
        const float4* rA = encb + (size_t)sA*(FF/4);
        float4 e0 = rA[lane], e1 = rA[64+lane], e2 = rA[128+lane], e3 = rA[192+lane];
        float da = (e0.x*we0.x + e0.y*we0.y + e0.z*we0.z + e0.w*we0.w)
                 + (e1.x*we1.x + e1.y*we1.y + e1.z*we1.z + e1.w*we1.w)
                 + (e2.x*we2.x + e2.y*we2.y + e2.z*we2.z + e2.w*we2.w)
                 + (e3.x*we3.x + e3.y*we3.y + e3.z*we3.z + e3.w*we3.w);
        #pragma unroll
        for (int off=32; off; off>>=1) da += __shfl_xor(da, off);
        float scA = da + bb;
        float pA = __expf(scA);
        l += pA;
        a0.x += pA*e0.x; a0.y += pA*e0.y; a0.z += pA*e0.z; a0.w += pA*e0.w;
        a1.x += pA*e1.x; a1.y += pA*e1.y; a1.z += pA*e1.z; a1.w += pA*e1.w;
        a2.x += pA*e2.x; a2.y += pA*e2.y; a2.z += pA*e2.z; a2.w += pA*e2.w;
        a3.x += pA*e3.x; a3.y += pA*e3.y; a3.z += pA*e3.z; a3.w += pA*e3.w;
        if (lane == 0) scores_out[b*SS + sA] = scA;
    }

    __shared__ float4 sacc[4][256];
    __shared__ float sl[4];
    if (lane==0) sl[w] = l;
    sacc[w][lane]     = a0;
    sacc[w][64+lane]  = a1;
    sacc[w][128+lane] = a2;
    sacc[w][192+lane] = a3;
    __syncthreads();
    float4 tot = sacc[0][tid];
    #pragma unroll
    for (int q=1;q<4;q++){ float4 u = sacc[q][tid]; tot.x+=u.x; tot.y+=u.y; tot.z+=u.z; tot.w+=u.w; }
    ((float4*)(pacc + (size_t)blockIdx.x*FF))[tid] = tot;
    if (tid==0) pl[blockIdx.x] = sl[0]+sl[1]+sl[2]+sl[3];
}

// ---------- C: merge partials -> xT; q0: scores->weights; q1: hT transpose; q2: out init ----------
__global__ __launch_bounds__(256) void kC(const float* __restrict__ pacc,
                                          const float* __restrict__ pl,
                                          const float* __restrict__ hidden,
                                          const float* __restrict__ out_b,
                                          float* __restrict__ xT,
                                          float* __restrict__ wout,
                                          float* __restrict__ hT,
                                          float* __restrict__ out)
{
    int b = blockIdx.x >> 2, q = blockIdx.x & 3, tid = threadIdx.x;
    float L = 0.f;
    #pragma unroll
    for (int c=0;c<NCHUNK;c++) L += pl[b*NCHUNK+c];
    float invL = 1.f/L;

    int f = q*256 + tid;
    float a = 0.f;
    #pragma unroll
    for (int c=0;c<NCHUNK;c++) a += pacc[((size_t)(b*NCHUNK+c))*FF + f];
    xT[(size_t)f*BB + b] = a*invL;

    if (q == 0){
        for (int t = tid; t < SS; t += 256){
            int idx2 = b*SS + t;
            wout[idx2] = __expf(wout[idx2]) * invL;
        }
    } else if (q == 1){
        for (int k = tid; k < HH; k += 256) hT[(size_t)k*BB + b] = hidden[(size_t)b*HH + k];
    } else if (q == 2){
        if (tid == 0) out[b] = out_b[0];
    }
}

// ---------- E1: combine-GEMM partials (j-tile 16, k-chunk 128), LDS-staged ----------
__global__ __launch_bounds__(256) void kE1(const float* __restrict__ xT,
                                           const float* __restrict__ cW,
                                           float* __restrict__ epart)
{
    __shared__ __align__(16) float Xl[KCH*64];   // 32 KB
    __shared__ __align__(16) float Wl[16*KCH];   // 8 KB
    int tid = threadIdx.x, lane = tid&63, w = tid>>6;
    int jb = blockIdx.x >> 3, kc = blockIdx.x & 7;
    int j0 = jb*16, k0 = kc*KCH;

    const float4* xs = (const float4*)(xT + (size_t)k0*BB);
    float4* xd = (float4*)Xl;
    #pragma unroll
    for (int r=tid; r<KCH*16; r+=256) xd[r] = xs[r];
    for (int idx=tid; idx<16*KCH; idx+=256){
        int row = idx>>7, kk = idx&127;
        Wl[idx] = cW[(size_t)(j0+row)*(FF+1) + 1 + k0 + kk];
    }
    __syncthreads();

    float acc[4] = {0.f,0.f,0.f,0.f};
    const float* wp = Wl + (w*4)*KCH;
    for (int kk=0; kk<KCH; kk+=4){
        float x0 = Xl[kk*64+lane], x1 = Xl[(kk+1)*64+lane];
        float x2 = Xl[(kk+2)*64+lane], x3 = Xl[(kk+3)*64+lane];
        #pragma unroll
        for (int jj=0;jj<4;jj++){
            float4 wv = *(const float4*)(wp + jj*KCH + kk);
            acc[jj] += x0*wv.x + x1*wv.y + x2*wv.z + x3*wv.w;
        }
    }
    #pragma unroll
    for (int jj=0;jj<4;jj++)
        epart[((size_t)kc*HH + j0 + w*4 + jj)*BB + lane] = acc[jj];
}

// ---------- E2: reduce partials + input column + bias, relu -> x2T ----------
__global__ __launch_bounds__(256) void kE2(const float* __restrict__ epart,
                                           const float* __restrict__ input,
                                           const float* __restrict__ cW,
                                           const float* __restrict__ cb,
                                           float* __restrict__ x2T)
{
    int tid = threadIdx.x, lane = tid&63, w = tid>>6;
    int j = blockIdx.x*4 + w;
    float s = 0.f;
    #pragma unroll
    for (int kc=0;kc<KSPLIT;kc++) s += epart[((size_t)kc*HH + j)*BB + lane];
    s += input[lane]*cW[(size_t)j*(FF+1)] + cb[j];
    x2T[(size_t)j*BB + lane] = fmaxf(s, 0.f);
}

// ---------- F1: GRU-GEMM partials (6144 rows, r-tile 16, k-chunk 128), LDS-staged ----------
__global__ __launch_bounds__(256) void kF1(const float* __restrict__ x2T,
                                           const float* __restrict__ hT,
                                           const float* __restrict__ W_ih,
                                           const float* __restrict__ W_hh,
                                           float* __restrict__ gpart)
{
    __shared__ __align__(16) float Xl[KCH*64];   // 32 KB
    __shared__ __align__(16) float Wl[16*KCH];   // 8 KB
    int tid = threadIdx.x, lane = tid&63, w = tid>>6;
    int rb = blockIdx.x >> 3, kc = blockIdx.x & 7;
    int r0 = rb*16, k0 = kc*KCH;
    bool ih = (r0 < 3*HH);
    const float* X  = ih ? x2T : hT;
    const float* Wb = ih ? (W_ih + (size_t)r0*HH) : (W_hh + (size_t)(r0-3*HH)*HH);

    const float4* xs = (const float4*)(X + (size_t)k0*BB);
    float4* xd = (float4*)Xl;
    #pragma unroll
    for (int r=tid; r<KCH*16; r+=256) xd[r] = xs[r];
    float4* wd = (float4*)Wl;
    #pragma unroll
    for (int idx4=tid; idx4<16*KCH/4; idx4+=256){
        int row = idx4>>5, kq = idx4&31;
        wd[idx4] = *(const float4*)(Wb + (size_t)row*HH + k0 + kq*4);
    }
    __syncthreads();

    float acc[4] = {0.f,0.f,0.f,0.f};
    const float* wp = Wl + (w*4)*KCH;
    for (int kk=0; kk<KCH; kk+=4){
        float x0 = Xl[kk*64+lane], x1 = Xl[(kk+1)*64+lane];
        float x2 = Xl[(kk+2)*64+lane], x3 = Xl[(kk+3)*64+lane];
        #pragma unroll
        for (int jj=0;jj<4;jj++){
            float4 wv = *(const float4*)(wp + jj*KCH + kk);
            acc[jj] += x0*wv.x + x1*wv.y + x2*wv.z + x3*wv.w;
        }
    }
    #pragma unroll
    for (int jj=0;jj<4;jj++)
        gpart[((size_t)kc*6*HH + r0 + w*4 + jj)*BB + lane] = acc[jj];
}

// ---------- F2: reduce partials, GRU gates, h_new, atomic out-projection ----------
__global__ __launch_bounds__(256) void kF2(const float* __restrict__ gpart,
                                           const float* __restrict__ b_ih,
                                           const float* __restrict__ b_hh,
                                           const float* __restrict__ hT,
                                           const float* __restrict__ out_W,
                                           float* __restrict__ hnew,
                                           float* __restrict__ out)
{
    int tid = threadIdx.x, lane = tid&63, w = tid>>6;
    int j = blockIdx.x*4 + w;
    float g[6];
    #pragma unroll
    for (int gi=0; gi<6; gi++){
        int row = (gi < 3) ? (gi*HH + j) : (3*HH + (gi-3)*HH + j);
        float s = 0.f;
        #pragma unroll
        for (int kc=0;kc<KSPLIT;kc++) s += gpart[((size_t)kc*6*HH + row)*BB + lane];
        g[gi] = s;
    }
    float r = sigm(g[0]+b_ih[j]        + g[3]+b_hh[j]);
    float z = sigm(g[1]+b_ih[HH+j]     + g[4]+b_hh[HH+j]);
    float n = tanhf(g[2]+b_ih[2*HH+j]  + r*(g[5]+b_hh[2*HH+j]));
    float hold = hT[(size_t)j*BB + lane];
    float hn = (1.f - z)*n + z*hold;
    hnew[(size_t)lane*HH + j] = hn;
    float pv = fmaxf(hn, 0.f) * out_W[j];
    __shared__ float red[4][64];
    red[w][lane] = pv;
    __syncthreads();
    if (w==0) atomicAdd(out + lane, red[0][lane]+red[1][lane]+red[2][lane]+red[3][lane]);
}

extern "C" void kernel_launch(void* const* d_in, const int* in_sizes, int n_in,
                              void* d_out, int out_size, void* d_ws, size_t ws_size,
                              hipStream_t stream) {
    const float* input     = (const float*)d_in[0];
    const float* hidden    = (const float*)d_in[1];
    const float* enc       = (const float*)d_in[2];
    const int*   mask      = (const int*)  d_in[3];
    const float* attn_W    = (const float*)d_in[4];
    const float* attn_b    = (const float*)d_in[5];
    const float* combine_W = (const float*)d_in[6];
    const float* combine_b = (const float*)d_in[7];
    const float* W_ih      = (const float*)d_in[8];
    const float* W_hh      = (const float*)d_in[9];
    const float* b_ih      = (const float*)d_in[10];
    const float* b_hh      = (const float*)d_in[11];
    const float* out_W     = (const float*)d_in[12];
    const float* out_b     = (const float*)d_in[13];

    float* out  = (float*)d_out;
    float* hnew = out + 64;            // (1,B,H)
    float* attw = out + 64 + BB*HH;    // (B,S,1) — raw scores between kM/kB and kC
    float* ws   = (float*)d_ws;
    int*   wsi  = (int*)d_ws;

    kM <<<64,   256, 0, stream>>>(mask, wsi+WS_IDX, wsi+WS_CNT, attw);
    kB <<<BB*NCHUNK, 256, 0, stream>>>(enc, attn_W, input, hidden, attn_b,
                                       wsi+WS_IDX, wsi+WS_CNT, attw, ws+WS_PACC, ws+WS_PL);
    kC <<<256,  256, 0, stream>>>(ws+WS_PACC, ws+WS_PL, hidden, out_b,
                                  ws+WS_XT, attw, ws+WS_HT, out);
    kE1<<<512,  256, 0, stream>>>(ws+WS_XT, combine_W, ws+WS_EPART);
    kE2<<<256,  256, 0, stream>>>(ws+WS_EPART, input, combine_W, combine_b, ws+WS_X2T);
    kF1<<<3072, 256, 0, stream>>>(ws+WS_X2T, ws+WS_HT, W_ih, W_hh, ws+WS_GPART);
    kF2<<<256,  256, 0, stream>>>(ws+WS_GPART, b_ih, b_hh, ws+WS_HT, out_W, hnew, out);
}